// Round 2
// baseline (99.652 us; speedup 1.0000x reference)
//
#include <hip/hip_runtime.h>

// BilinearJoints: closed-form 6x6 expm (see round-0 derivation).
//   SSout = exp(A dt) @ SS + phi1(A dt) @ (0, B10*dt)
// with A = [[0,1],[A10,A11]]; f(A dt) = alpha*I + beta*(A dt), alpha/beta from
// eigenvalues s +/- sqrt(s^2 - d), s = A11 dt/2, d = -A10 dt^2 > 0.
//
// Round-2 refactor: B_F*Ms expanded as polynomial in alpha:
//   Kact_m = c0 + a*c1,   c0 = K0*Ms^2, c1 = K1*Ms^2
//   BF*Ms  = d0 + a*d1 + a^2*d2 - |ss0|*(c0 + a*c1)
//     d0 = Ms*K0*L0, d1 = Ms*(K0*L1+K1*L0), d2 = 2*Ms*K1*L1
// => Ksum = C0 + sum(a*c1);  bacc = D0 + sum(a*(d1 + a*d2)) - |ss0|*Ksum
// Per-joint constants computed once per block into LDS by wave 0.

constexpr int BATCH = 16384;
constexpr int NJ = 64;
constexpr int NM = 8;
constexpr float DT = 0.0166667f;

__device__ __forceinline__ float rcpf(float x) { return __builtin_amdgcn_rcpf(x); }

__global__ __launch_bounds__(256) void bilinear_joints_kernel(
    const float* __restrict__ SS,
    const float* __restrict__ Alphas,
    const float* __restrict__ K0s,
    const float* __restrict__ K1s,
    const float* __restrict__ L0s,
    const float* __restrict__ L1s,
    const float* __restrict__ Ms,
    const float* __restrict__ Iarr,
    const float* __restrict__ Bjarr,
    const float* __restrict__ Kjarr,
    float* __restrict__ out0,
    float* __restrict__ out1)
{
    // per-joint constants: [0..7]=c1, [8..15]=d1, [16..23]=d2,
    // [24]=C0, [25]=D0, [26]=ddk, [27]=dd0, [28]=sc, [29]=sb, [30]=I, [31]=bscale
    __shared__ float sj[NJ][36];   // stride 144B: 16B-aligned, bank-rotating

    const int tid = threadIdx.x;

    if (tid < NJ) {
        const int j = tid;
        const float4 K0a = *reinterpret_cast<const float4*>(K0s + 8 * j);
        const float4 K0b = *reinterpret_cast<const float4*>(K0s + 8 * j + 4);
        const float4 K1a = *reinterpret_cast<const float4*>(K1s + 8 * j);
        const float4 K1b = *reinterpret_cast<const float4*>(K1s + 8 * j + 4);
        const float4 L0a = *reinterpret_cast<const float4*>(L0s + 8 * j);
        const float4 L0b = *reinterpret_cast<const float4*>(L0s + 8 * j + 4);
        const float4 L1a = *reinterpret_cast<const float4*>(L1s + 8 * j);
        const float4 L1b = *reinterpret_cast<const float4*>(L1s + 8 * j + 4);
        const float4 Msa = *reinterpret_cast<const float4*>(Ms + 8 * j);
        const float4 Msb = *reinterpret_cast<const float4*>(Ms + 8 * j + 4);

        const float k0[NM] = {K0a.x, K0a.y, K0a.z, K0a.w, K0b.x, K0b.y, K0b.z, K0b.w};
        const float k1[NM] = {K1a.x, K1a.y, K1a.z, K1a.w, K1b.x, K1b.y, K1b.z, K1b.w};
        const float l0[NM] = {L0a.x, L0a.y, L0a.z, L0a.w, L0b.x, L0b.y, L0b.z, L0b.w};
        const float l1[NM] = {L1a.x, L1a.y, L1a.z, L1a.w, L1b.x, L1b.y, L1b.z, L1b.w};
        const float ms[NM] = {Msa.x, Msa.y, Msa.z, Msa.w, Msb.x, Msb.y, Msb.z, Msb.w};

        float C0 = 0.0f, D0 = 0.0f;
#pragma unroll
        for (int m = 0; m < NM; ++m) {
            const float mv  = ms[m];
            const float ms2 = mv * mv;
            sj[j][m]      = k1[m] * ms2;                                // c1
            sj[j][8 + m]  = mv * fmaf(k0[m], l1[m], k1[m] * l0[m]);     // d1
            sj[j][16 + m] = 2.0f * mv * k1[m] * l1[m];                  // d2
            C0 = fmaf(k0[m], ms2, C0);
            D0 = fmaf(mv * k0[m], l0[m], D0);
        }
        const float Iv   = Iarr[j];
        const float Bjv  = Bjarr[j];
        const float Kjv  = Kjarr[j];
        const float invI = rcpf(Iv);
        const float ddk  = invI * DT * DT;       // d = Ksum*ddk + dd0
        const float sc   = -0.5f * invI * DT;    // s = Dmp*sc + sb
        sj[j][24] = C0;
        sj[j][25] = D0;
        sj[j][26] = ddk;
        sj[j][27] = Kjv * ddk;
        sj[j][28] = sc;
        sj[j][29] = Bjv * sc;
        sj[j][30] = Iv;
        sj[j][31] = invI * DT;                   // bscale: B10*dt = bacc*bscale
    }
    __syncthreads();

    const int idx = blockIdx.x * blockDim.x + tid;  // b*NJ + j
    if (idx >= BATCH * NJ) return;
    const int j = tid & (NJ - 1);

    const float2 ss  = *reinterpret_cast<const float2*>(SS + 2 * idx);
    const float4 a0v = *reinterpret_cast<const float4*>(Alphas + 8 * idx);
    const float4 a1v = *reinterpret_cast<const float4*>(Alphas + 8 * idx + 4);

    const float4* p = reinterpret_cast<const float4*>(&sj[j][0]);
    const float4 c1a = p[0], c1b = p[1];
    const float4 d1a = p[2], d1b = p[3];
    const float4 d2a = p[4], d2b = p[5];
    const float4 s0  = p[6], s1  = p[7];
    const float C0 = s0.x, D0 = s0.y, ddk = s0.z, dd0 = s0.w;
    const float sc = s1.x, sb = s1.y, Iv = s1.z, bscale = s1.w;

    const float al[NM] = {a0v.x, a0v.y, a0v.z, a0v.w, a1v.x, a1v.y, a1v.z, a1v.w};
    const float c1[NM] = {c1a.x, c1a.y, c1a.z, c1a.w, c1b.x, c1b.y, c1b.z, c1b.w};
    const float d1[NM] = {d1a.x, d1a.y, d1a.z, d1a.w, d1b.x, d1b.y, d1b.z, d1b.w};
    const float d2[NM] = {d2a.x, d2a.y, d2a.z, d2a.w, d2b.x, d2b.y, d2b.z, d2b.w};

    float ks = 0.0f, bb = 0.0f;
#pragma unroll
    for (int m = 0; m < NM; ++m) {
        const float a = fminf(fmaxf(al[m], 0.0f), 1.0f);
        ks = fmaf(a, c1[m], ks);
        bb = fmaf(a, fmaf(a, d2[m], d1[m]), bb);
    }
    const float absSS0 = fabsf(ss.x);
    const float Ksum = C0 + ks;
    const float bacc = D0 + bb - absSS0 * Ksum;      // = sum(B_F*Ms)

    const float d   = fmaf(Ksum, ddk, dd0);          // -A10*dt^2 > 0
    const float Dmp = 2.0f * sqrtf(Ksum * Iv);
    const float s   = fmaf(Dmp, sc, sb);             // A11*dt/2
    const float Delta = fmaf(s, s, -d);
    const float es  = __expf(s);

    float alphaE, betaE, alphaP, betaP;
    if (Delta < 0.0f) {
        // complex pair s +/- i r,  r^2 = d - s^2
        const float r = sqrtf(-Delta);
        float si, co;
        __sincosf(r, &si, &co);
        const float esco = es * co;
        const float essi = es * si;
        const float sinc = (r > 1e-6f) ? essi * rcpf(r) : es;  // es*sin(r)/r
        betaE  = sinc;
        alphaE = esco - sinc * s;
        const float invd = rcpf(d);
        betaP  = fmaf(s, sinc, 1.0f - esco) * invd;
        const float ref1 = fmaf(s, esco - 1.0f, essi * r) * invd;
        alphaP = ref1 - betaP * s;
    } else {
        // real pair s +/- r (essentially unreachable for these input ranges)
        const float r   = sqrtf(Delta);
        const float er  = __expf(r);
        const float ier = rcpf(er);
        const float ch  = 0.5f * (er + ier);
        const float sh  = 0.5f * (er - ier);
        const float sinch = (r > 1e-6f) ? sh * rcpf(r) : 1.0f;
        betaE  = es * sinch;
        alphaE = es * ch - betaE * s;
        const float lam1 = s + r, lam2 = s - r;
        const float f1 = (fabsf(lam1) > 1e-4f) ? (es * er - 1.0f) * rcpf(lam1)
                                               : fmaf(0.5f, lam1, 1.0f);
        const float f2 = (fabsf(lam2) > 1e-4f) ? (es * ier - 1.0f) * rcpf(lam2)
                                               : fmaf(0.5f, lam2, 1.0f);
        if (r > 1e-5f) {
            betaP = (f1 - f2) * 0.5f * rcpf(r);
        } else {
            const float s2 = s * s;
            betaP = (s2 > 1e-12f) ? (fmaf(es, s - 1.0f, 1.0f)) * rcpf(s2) : 0.5f;
        }
        alphaP = 0.5f * (f1 + f2) - betaP * s;
    }

    // Ad = alphaE*I + betaE*(A dt);  A10*dt = -d/dt, A11*dt = 2s
    constexpr float INVDT = 1.0f / DT;
    const float Ad00 = alphaE;
    const float Ad01 = betaE * DT;
    const float Ad10 = -betaE * d * INVDT;
    const float Ad11 = fmaf(2.0f * betaE, s, alphaE);

    const float c1v = bacc * bscale;                 // B10*dt
    const float w0  = betaP * DT * c1v;
    const float w1  = fmaf(2.0f * betaP, s, alphaP) * c1v;

    const float o0 = fmaf(Ad00, ss.x, fmaf(Ad01, ss.y, w0));
    const float o1 = fmaf(Ad10, ss.x, fmaf(Ad11, ss.y, w1));

    out0[idx] = o0;
    float2 o; o.x = o0; o.y = o1;
    *reinterpret_cast<float2*>(out1 + 2 * idx) = o;
}

extern "C" void kernel_launch(void* const* d_in, const int* in_sizes, int n_in,
                              void* d_out, int out_size, void* d_ws, size_t ws_size,
                              hipStream_t stream) {
    const float* SS     = (const float*)d_in[0];
    const float* Alphas = (const float*)d_in[1];
    const float* K0s    = (const float*)d_in[2];
    const float* K1s    = (const float*)d_in[3];
    const float* L0s    = (const float*)d_in[4];
    const float* L1s    = (const float*)d_in[5];
    const float* Msp    = (const float*)d_in[6];
    const float* Iarr   = (const float*)d_in[7];
    const float* Bjarr  = (const float*)d_in[8];
    const float* Kjarr  = (const float*)d_in[9];

    float* out0 = (float*)d_out;                  // (BATCH, NJ)
    float* out1 = out0 + BATCH * NJ;              // (BATCH, NJ, 2)

    const int total = BATCH * NJ;
    const int block = 256;
    const int grid = (total + block - 1) / block; // 4096 blocks

    bilinear_joints_kernel<<<grid, block, 0, stream>>>(
        SS, Alphas, K0s, K1s, L0s, L1s, Msp, Iarr, Bjarr, Kjarr, out0, out1);
}